// Round 1
// baseline (1131.876 us; speedup 1.0000x reference)
//
#include <hip/hip_runtime.h>
#include <hip/hip_bf16.h>
#include <math.h>

#define NB 16
#define NC 64
#define NH 160
#define NW 160

__device__ __forceinline__ float ldval(const float* p) { return *p; }
__device__ __forceinline__ float ldval(const __hip_bfloat16* p) { return __bfloat162float(*p); }

// ---------------------------------------------------------------------------
// Conv 3x3 SAME, stride 1, fused epilogue.
//  FINAL=false: out(bf16) = silu(bn1(conv(x)))          [y]
//  FINAL=true : out(f32)  = x + relu(bn2(scores*conv(y) + y))
// Block = one (b,h) output row, all 64 co x 160 w. 256 threads:
//   t = cg*16 + wg ; thread computes co = cg*4+cc (cc=0..3), w = wg*10+p (p=0..9)
// LDS: input tile for 32-ci chunk: [32][3 rows][162 padded] f32 = 62,208 B.
// ---------------------------------------------------------------------------
template<typename TIN, bool FINAL>
__global__ __launch_bounds__(256, 2) void conv3x3_fused(
    const TIN* __restrict__ in, const float* __restrict__ wconv,
    const float* __restrict__ gg, const float* __restrict__ bbeta,
    const float* __restrict__ mmean, const float* __restrict__ vvar,
    void* __restrict__ outv, const float* __restrict__ scores,
    const float* __restrict__ xres)
{
  __shared__ float lds[32 * 3 * 162];
  const int bh = blockIdx.x;
  const int b = bh / NH, h = bh % NH;
  const int t = threadIdx.x;
  const int cg = t >> 4, wg = t & 15;
  const int w0 = wg * 10;

  float acc[4][10];
#pragma unroll
  for (int i = 0; i < 4; ++i)
#pragma unroll
    for (int j = 0; j < 10; ++j) acc[i][j] = 0.f;

  const TIN* inb = in + (size_t)b * NC * NH * NW;

  for (int chunk = 0; chunk < 2; ++chunk) {
    const int cbase = chunk * 32;
    __syncthreads();
    for (int idx = t; idx < 32 * 3 * 162; idx += 256) {
      int lw = idx % 162;
      int rr = (idx / 162) % 3;
      int ci = idx / (162 * 3);
      int wsrc = lw - 1;
      int hsrc = h - 1 + rr;
      float val = 0.f;
      if ((unsigned)wsrc < (unsigned)NW && (unsigned)hsrc < (unsigned)NH)
        val = ldval(&inb[((size_t)(cbase + ci) * NH + hsrc) * NW + wsrc]);
      lds[idx] = val;
    }
    __syncthreads();
    for (int ci = 0; ci < 32; ++ci) {
#pragma unroll
      for (int r = 0; r < 3; ++r) {
        const float* lrow = &lds[(ci * 3 + r) * 162 + w0];
        float xr[12];
#pragma unroll
        for (int jj = 0; jj < 6; ++jj) {   // base is 8B-aligned (162 even, w0 even)
          float2 v2 = *(const float2*)(lrow + jj * 2);
          xr[jj * 2] = v2.x; xr[jj * 2 + 1] = v2.y;
        }
#pragma unroll
        for (int cc = 0; cc < 4; ++cc) {
          const int co = cg * 4 + cc;
          const float* wp = wconv + (((size_t)co * NC + cbase + ci) * 3 + r) * 3;
          const float wa = wp[0], wb = wp[1], wc = wp[2];
#pragma unroll
          for (int p = 0; p < 10; ++p)
            acc[cc][p] = fmaf(wa, xr[p], fmaf(wb, xr[p + 1], fmaf(wc, xr[p + 2], acc[cc][p])));
        }
      }
    }
  }

#pragma unroll
  for (int cc = 0; cc < 4; ++cc) {
    const int co = cg * 4 + cc;
    const float sc = gg[co] * rsqrtf(vvar[co] + 1e-5f);
    const float sh = bbeta[co] - mmean[co] * sc;
    const size_t base = (((size_t)b * NC + co) * NH + h) * NW + w0;
    if constexpr (!FINAL) {
      __hip_bfloat16* yout = (__hip_bfloat16*)outv;
#pragma unroll
      for (int p = 0; p < 10; ++p) {
        float v = sc * acc[cc][p] + sh;
        float s = v / (1.f + __expf(-v));
        yout[base + p] = __float2bfloat16(s);
      }
    } else {
      float* outp = (float*)outv;
      const float s = scores[b * NC + co];
#pragma unroll
      for (int p = 0; p < 10; ++p) {
        float rv = s * acc[cc][p] + ldval(&in[base + p]);   // in == y here
        float rb = sc * rv + sh;
        rb = fmaxf(rb, 0.f);
        outp[base + p] = xres[base + p] + rb;
      }
    }
  }
}

// ycol[b,c,w] = sum_h y[b,c,h,w]
__global__ void colsum_kernel(const __hip_bfloat16* __restrict__ y, float* __restrict__ ycol) {
  int id = blockIdx.x * blockDim.x + threadIdx.x;
  if (id >= NB * NC * NW) return;
  int w = id % NW; int bc = id / NW;
  const __hip_bfloat16* p = y + (size_t)bc * NH * NW + w;
  float s = 0.f;
  for (int hh = 0; hh < NH; ++hh) s += __bfloat162float(p[(size_t)hh * NW]);
  ycol[id] = s;
}

// wks[o] = sum_j wk[j][o], o = (i*3+kh)*3+kw
__global__ void wksum_kernel(const float* __restrict__ wk, float* __restrict__ wks) {
  int o = blockIdx.x * blockDim.x + threadIdx.x;
  if (o >= 576) return;
  float s = 0.f;
  for (int j = 0; j < NC; ++j) s += wk[(size_t)j * 576 + o];
  wks[o] = s;
}

// One block per b: build Z (colsums w/ edge-row corrections, padded), then
// k_sum, then U, then f_scores -> softmax -> scores[b,c].
__global__ __launch_bounds__(256, 1) void scores_kernel(
    const __hip_bfloat16* __restrict__ y, const float* __restrict__ ycol,
    const float* __restrict__ wks, const float* __restrict__ wq,
    float* __restrict__ scores)
{
  __shared__ float Z[NC * 3 * 162];
  __shared__ float ks[NW];
  __shared__ float U[576];
  const int b = blockIdx.x, t = threadIdx.x;

  for (int idx = t; idx < NC * 3 * 162; idx += 256) {
    int lw = idx % 162;
    int kh = (idx / 162) % 3;
    int i  = idx / (162 * 3);
    int w = lw - 1;
    float val = 0.f;
    if ((unsigned)w < (unsigned)NW) {
      val = ycol[((size_t)b * NC + i) * NW + w];
      if (kh == 0) val -= __bfloat162float(y[(((size_t)b * NC + i) * NH + (NH - 1)) * NW + w]);
      if (kh == 2) val -= __bfloat162float(y[(((size_t)b * NC + i) * NH) * NW + w]);
    }
    Z[idx] = val;
  }
  __syncthreads();

  if (t < NW) {
    float s = 0.f;
    for (int ik = 0; ik < NC * 3; ++ik) {
      const float* zr = &Z[ik * 162 + t];
      const float* wp = &wks[ik * 3];
      s += wp[0] * zr[0] + wp[1] * zr[1] + wp[2] * zr[2];
    }
    ks[t] = s;
  }
  __syncthreads();

  for (int o = t; o < 576; o += 256) {
    int kw = o % 3; int ik = o / 3;
    const float* zr = &Z[ik * 162 + kw];
    float s = 0.f;
    for (int w = 0; w < NW; ++w) s += zr[w] * ks[w];
    U[o] = s;
  }
  __syncthreads();

  if (t < NC) {
    const float* wp = wq + (size_t)t * 576;
    float s = 0.f;
    for (int o = 0; o < 576; ++o) s += wp[o] * U[o];
    const float scale = 1.0f / (sqrtf((float)NW) * (float)NH * (float)NH);
    float f = s * scale;
    float mx = f;
#pragma unroll
    for (int off = 32; off; off >>= 1) mx = fmaxf(mx, __shfl_xor(mx, off));
    float e = __expf(f - mx);
    float sm = e;
#pragma unroll
    for (int off = 32; off; off >>= 1) sm += __shfl_xor(sm, off);
    scores[b * NC + t] = e / sm;
  }
}

extern "C" void kernel_launch(void* const* d_in, const int* in_sizes, int n_in,
                              void* d_out, int out_size, void* d_ws, size_t ws_size,
                              hipStream_t stream) {
  const float* x  = (const float*)d_in[0];
  const float* w1 = (const float*)d_in[1];
  const float* g1 = (const float*)d_in[2];
  const float* b1 = (const float*)d_in[3];
  const float* m1 = (const float*)d_in[4];
  const float* v1 = (const float*)d_in[5];
  const float* wq = (const float*)d_in[6];
  const float* wk = (const float*)d_in[7];
  const float* wv = (const float*)d_in[8];
  const float* g2 = (const float*)d_in[9];
  const float* b2 = (const float*)d_in[10];
  const float* m2 = (const float*)d_in[11];
  const float* v2 = (const float*)d_in[12];
  float* out = (float*)d_out;

  // ws layout: y (bf16, 52.4 MB) | ycol f32 | wksum f32 | scores f32  (~53 MB)
  __hip_bfloat16* y = (__hip_bfloat16*)d_ws;
  float* fws  = (float*)((char*)d_ws + (size_t)NB * NC * NH * NW * sizeof(__hip_bfloat16));
  float* ycol = fws;                 // NB*NC*NW
  float* wks  = ycol + NB * NC * NW; // 576
  float* scr  = wks + 576;           // NB*NC

  conv3x3_fused<float, false><<<dim3(NB * NH), 256, 0, stream>>>(
      x, w1, g1, b1, m1, v1, (void*)y, nullptr, nullptr);
  colsum_kernel<<<dim3((NB * NC * NW + 255) / 256), 256, 0, stream>>>(y, ycol);
  wksum_kernel<<<dim3(3), 256, 0, stream>>>(wk, wks);
  scores_kernel<<<dim3(NB), 256, 0, stream>>>(y, ycol, wks, wq, scr);
  conv3x3_fused<__hip_bfloat16, true><<<dim3(NB * NH), 256, 0, stream>>>(
      y, wv, g2, b2, m2, v2, (void*)out, scr, x);
}

// Round 2
// 272.311 us; speedup vs baseline: 4.1565x; 4.1565x over previous
//
#include <hip/hip_runtime.h>
#include <hip/hip_bf16.h>
#include <math.h>

#define NB 16
#define NC 64
#define NH 160
#define NW 160

typedef __attribute__((ext_vector_type(8))) short bf16x8;
typedef __attribute__((ext_vector_type(4))) float f32x4;
typedef __attribute__((ext_vector_type(4))) unsigned int u32x4;

__device__ __forceinline__ unsigned short f2bf(float v) {
  union { __hip_bfloat16 b; unsigned short u; } cv;
  cv.b = __float2bfloat16(v);
  return cv.u;
}
__device__ __forceinline__ unsigned short ldbits(const float* p) { return f2bf(*p); }
__device__ __forceinline__ unsigned short ldbits(const unsigned short* p) { return *p; }

// Pack conv weights (OIHW fp32) into exact A-fragment order for
// mfma_f32_16x16x32_bf16:  apk[((ct*18 + ks)*64 + lane)*8 + j]
//   co = ct*16 + (lane&15); ci = (ks/9)*32 + (lane>>4)*8 + j; tap = ks%9.
__global__ void pack_w_kernel(const float* __restrict__ w, unsigned short* __restrict__ apk) {
  int idx = blockIdx.x * 256 + threadIdx.x;
  if (idx >= 4 * 18 * 64 * 8) return;
  int j = idx & 7;
  int l = (idx >> 3) & 63;
  int rest = idx >> 9;
  int ks = rest % 18, ct = rest / 18;
  int co = ct * 16 + (l & 15);
  int ci = (ks / 9) * 32 + (l >> 4) * 8 + j;
  int tap = ks % 9, kh = tap / 3, kw = tap % 3;
  apk[idx] = f2bf(w[(((size_t)co * NC + ci) * 3 + kh) * 3 + kw]);
}

// ---------------------------------------------------------------------------
// Implicit-GEMM 3x3 SAME conv via MFMA 16x16x32 bf16.
// Block: (b, h0..h0+1) x all 160 w. 4 waves = 2 h x 2 w-halves(80).
// Wave tile: 64 co x 80 w = 4 ct x 5 wt fragments. K = 2 ci-chunks x 9 taps.
// LDS input tile: [4 rows][4 slots][162 wc][8 ci] bf16 = 41.5 KB.
// ---------------------------------------------------------------------------
template<typename TIN, bool FINAL>
__global__ __launch_bounds__(256, 3) void conv3x3_mfma(
    const TIN* __restrict__ in, const unsigned short* __restrict__ apk,
    const float* __restrict__ gg, const float* __restrict__ bbeta,
    const float* __restrict__ mmean, const float* __restrict__ vvar,
    void* __restrict__ outv, const float* __restrict__ scores,
    const float* __restrict__ xres, const __hip_bfloat16* __restrict__ yres)
{
  __shared__ unsigned short smem[4 * 4 * 162 * 8];
  __shared__ float scL[NC], shL[NC], scoreL[NC];

  const int t = threadIdx.x;
  // bijective XCD swizzle: nwg = 1280 = 8 * 160
  const int g = blockIdx.x;
  const int swz = (g & 7) * 160 + (g >> 3);
  const int b = swz / (NH / 2);
  const int h0 = (swz % (NH / 2)) * 2;

  if (t < NC) {
    float s = gg[t] * rsqrtf(vvar[t] + 1e-5f);
    scL[t] = s;
    shL[t] = bbeta[t] - mmean[t] * s;
    if (FINAL) scoreL[t] = scores[b * NC + t];
  }

  const int lane = t & 63, wave = t >> 6;
  const int q = lane >> 4, col = lane & 15;
  const int hloc = wave >> 1, w00 = (wave & 1) * 80;

  f32x4 acc[4][5];
#pragma unroll
  for (int i = 0; i < 4; ++i)
#pragma unroll
    for (int j = 0; j < 5; ++j) acc[i][j] = (f32x4){0.f, 0.f, 0.f, 0.f};

  const TIN* inb = in + (size_t)b * NC * NH * NW;

  for (int chunk = 0; chunk < 2; ++chunk) {
    const int cbase = chunk * 32;
    __syncthreads();
    // stage: 648 cells of (row r, wcol wc), each = 32 ci as 4x 16B slot writes
    for (int c = t; c < 4 * 162; c += 256) {
      int r = c / 162, wc = c % 162;
      int hsrc = h0 - 1 + r, wsrc = wc - 1;
      bool ok = ((unsigned)hsrc < (unsigned)NH) & ((unsigned)wsrc < (unsigned)NW);
      const TIN* p0 = inb + (size_t)cbase * NH * NW + (size_t)hsrc * NW + wsrc;
#pragma unroll
      for (int s = 0; s < 4; ++s) {
        u32x4 d;
#pragma unroll
        for (int kk = 0; kk < 4; ++kk) {
          unsigned short u0 = 0, u1 = 0;
          if (ok) {
            u0 = ldbits(p0 + (size_t)(s * 8 + kk * 2) * NH * NW);
            u1 = ldbits(p0 + (size_t)(s * 8 + kk * 2 + 1) * NH * NW);
          }
          d[kk] = (unsigned)u0 | ((unsigned)u1 << 16);
        }
        *(u32x4*)&smem[((r * 4 + s) * 162 + wc) * 8] = d;
      }
    }
    __syncthreads();

#pragma unroll 3
    for (int tap = 0; tap < 9; ++tap) {
      const int kh = tap / 3, kw = tap - 3 * (tap / 3);
      const int rr = ((hloc + kh) * 4 + q) * 162;
      bf16x8 a[4], bb[5];
#pragma unroll
      for (int ct = 0; ct < 4; ++ct)
        a[ct] = *(const bf16x8*)&apk[(((ct * 18 + chunk * 9 + tap) * 64) + lane) * 8];
#pragma unroll
      for (int wt = 0; wt < 5; ++wt)
        bb[wt] = *(const bf16x8*)&smem[(rr + w00 + wt * 16 + col + kw) * 8];
#pragma unroll
      for (int ct = 0; ct < 4; ++ct)
#pragma unroll
        for (int wt = 0; wt < 5; ++wt)
          acc[ct][wt] = __builtin_amdgcn_mfma_f32_16x16x32_bf16(a[ct], bb[wt], acc[ct][wt], 0, 0, 0);
    }
  }

  // epilogue: C frag mapping col=lane&15 (w), row=(lane>>4)*4+reg (co)
  const int h = h0 + hloc;
#pragma unroll
  for (int ct = 0; ct < 4; ++ct) {
#pragma unroll
    for (int reg = 0; reg < 4; ++reg) {
      const int co = ct * 16 + q * 4 + reg;
      const float sc = scL[co], sh = shL[co];
#pragma unroll
      for (int wt = 0; wt < 5; ++wt) {
        const int w = w00 + wt * 16 + col;
        const size_t idx = (((size_t)b * NC + co) * NH + h) * NW + w;
        float v = acc[ct][wt][reg];
        if constexpr (!FINAL) {
          float z = sc * v + sh;
          float sv = z / (1.f + __expf(-z));
          ((__hip_bfloat16*)outv)[idx] = __float2bfloat16(sv);
        } else {
          float rv = scoreL[co] * v + __bfloat162float(yres[idx]);
          float rb = sc * rv + sh;
          rb = fmaxf(rb, 0.f);
          ((float*)outv)[idx] = xres[idx] + rb;
        }
      }
    }
  }
}

// ycol[b,c,w] = sum_h y[b,c,h,w]
__global__ void colsum_kernel(const __hip_bfloat16* __restrict__ y, float* __restrict__ ycol) {
  int id = blockIdx.x * blockDim.x + threadIdx.x;
  if (id >= NB * NC * NW) return;
  int w = id % NW; int bc = id / NW;
  const __hip_bfloat16* p = y + (size_t)bc * NH * NW + w;
  float s = 0.f;
  for (int hh = 0; hh < NH; ++hh) s += __bfloat162float(p[(size_t)hh * NW]);
  ycol[id] = s;
}

// wks[o] = sum_j wk[j][o]
__global__ void wksum_kernel(const float* __restrict__ wk, float* __restrict__ wks) {
  int o = blockIdx.x * blockDim.x + threadIdx.x;
  if (o >= 576) return;
  float s = 0.f;
  for (int j = 0; j < NC; ++j) s += wk[(size_t)j * 576 + o];
  wks[o] = s;
}

__global__ __launch_bounds__(256, 1) void scores_kernel(
    const __hip_bfloat16* __restrict__ y, const float* __restrict__ ycol,
    const float* __restrict__ wks, const float* __restrict__ wq,
    float* __restrict__ scores)
{
  __shared__ float Z[NC * 3 * 162];
  __shared__ float ks[NW];
  __shared__ float U[576];
  const int b = blockIdx.x, t = threadIdx.x;

  for (int idx = t; idx < NC * 3 * 162; idx += 256) {
    int lw = idx % 162;
    int kh = (idx / 162) % 3;
    int i  = idx / (162 * 3);
    int w = lw - 1;
    float val = 0.f;
    if ((unsigned)w < (unsigned)NW) {
      val = ycol[((size_t)b * NC + i) * NW + w];
      if (kh == 0) val -= __bfloat162float(y[(((size_t)b * NC + i) * NH + (NH - 1)) * NW + w]);
      if (kh == 2) val -= __bfloat162float(y[(((size_t)b * NC + i) * NH) * NW + w]);
    }
    Z[idx] = val;
  }
  __syncthreads();

  if (t < NW) {
    float s = 0.f;
    for (int ik = 0; ik < NC * 3; ++ik) {
      const float* zr = &Z[ik * 162 + t];
      const float* wp = &wks[ik * 3];
      s += wp[0] * zr[0] + wp[1] * zr[1] + wp[2] * zr[2];
    }
    ks[t] = s;
  }
  __syncthreads();

  for (int o = t; o < 576; o += 256) {
    int kw = o % 3; int ik = o / 3;
    const float* zr = &Z[ik * 162 + kw];
    float s = 0.f;
    for (int w = 0; w < NW; ++w) s += zr[w] * ks[w];
    U[o] = s;
  }
  __syncthreads();

  if (t < NC) {
    const float* wp = wq + (size_t)t * 576;
    float s = 0.f;
    for (int o = 0; o < 576; ++o) s += wp[o] * U[o];
    const float scale = 1.0f / (sqrtf((float)NW) * (float)NH * (float)NH);
    float f = s * scale;
    float mx = f;
#pragma unroll
    for (int off = 32; off; off >>= 1) mx = fmaxf(mx, __shfl_xor(mx, off));
    float e = __expf(f - mx);
    float sm = e;
#pragma unroll
    for (int off = 32; off; off >>= 1) sm += __shfl_xor(sm, off);
    scores[b * NC + t] = e / sm;
  }
}

extern "C" void kernel_launch(void* const* d_in, const int* in_sizes, int n_in,
                              void* d_out, int out_size, void* d_ws, size_t ws_size,
                              hipStream_t stream) {
  const float* x  = (const float*)d_in[0];
  const float* w1 = (const float*)d_in[1];
  const float* g1 = (const float*)d_in[2];
  const float* b1 = (const float*)d_in[3];
  const float* m1 = (const float*)d_in[4];
  const float* v1 = (const float*)d_in[5];
  const float* wq = (const float*)d_in[6];
  const float* wk = (const float*)d_in[7];
  const float* wv = (const float*)d_in[8];
  const float* g2 = (const float*)d_in[9];
  const float* b2 = (const float*)d_in[10];
  const float* m2 = (const float*)d_in[11];
  const float* v2 = (const float*)d_in[12];
  float* out = (float*)d_out;

  // ws: apk1 | apk2 | ycol | wks | scr | y(bf16)
  unsigned short* apk1 = (unsigned short*)d_ws;
  unsigned short* apk2 = apk1 + 36864;
  float* ycol = (float*)(apk2 + 36864);
  float* wks  = ycol + NB * NC * NW;
  float* scr  = wks + 576;
  __hip_bfloat16* y = (__hip_bfloat16*)(scr + NB * NC);

  pack_w_kernel<<<dim3(144), 256, 0, stream>>>(w1, apk1);
  pack_w_kernel<<<dim3(144), 256, 0, stream>>>(wv, apk2);

  conv3x3_mfma<float, false><<<dim3(NB * NH / 2), 256, 0, stream>>>(
      x, apk1, g1, b1, m1, v1, (void*)y, nullptr, nullptr, nullptr);

  colsum_kernel<<<dim3((NB * NC * NW + 255) / 256), 256, 0, stream>>>(y, ycol);
  wksum_kernel<<<dim3(3), 256, 0, stream>>>(wk, wks);
  scores_kernel<<<dim3(NB), 256, 0, stream>>>(y, ycol, wks, wq, scr);

  conv3x3_mfma<unsigned short, true><<<dim3(NB * NH / 2), 256, 0, stream>>>(
      (const unsigned short*)y, apk2, g2, b2, m2, v2, (void*)out, scr, x, y);
}

// Round 3
// 256.880 us; speedup vs baseline: 4.4062x; 1.0601x over previous
//
#include <hip/hip_runtime.h>
#include <hip/hip_bf16.h>
#include <math.h>

#define NB 16
#define NC 64
#define NH 160
#define NW 160

typedef __attribute__((ext_vector_type(8))) short bf16x8;
typedef __attribute__((ext_vector_type(4))) float f32x4;
typedef __attribute__((ext_vector_type(8))) unsigned short u16x8;
typedef __attribute__((ext_vector_type(4))) unsigned short u16x4;

__device__ __forceinline__ unsigned short f2bf(float v) {
  union { __hip_bfloat16 b; unsigned short u; } cv; cv.b = __float2bfloat16(v); return cv.u;
}
__device__ __forceinline__ float bf2f(unsigned short u) {
  union { unsigned u; float f; } cv; cv.u = ((unsigned)u) << 16; return cv.f;
}

// ---------------------------------------------------------------------------
// Pack conv weights (OIHW fp32) -> A-fragment order for mfma_f32_16x16x32_bf16
// apk[((ct*18 + ks)*64 + lane)*8 + j];  ks = (kh*3+kw)*2 + cih
// co = ct*16 + (lane&15); ci = cih*32 + (lane>>4)*8 + j
// ---------------------------------------------------------------------------
__global__ void pack_w_kernel(const float* __restrict__ w, unsigned short* __restrict__ apk) {
  int idx = blockIdx.x * 256 + threadIdx.x;
  if (idx >= 4 * 18 * 64 * 8) return;
  int j = idx & 7, l = (idx >> 3) & 63, rest = idx >> 9;
  int ks = rest % 18, ct = rest / 18;
  int cih = ks & 1, tap = ks >> 1, kh = tap / 3, kw = tap % 3;
  int co = ct * 16 + (l & 15), ci = cih * 32 + (l >> 4) * 8 + j;
  apk[idx] = f2bf(w[(((size_t)co * NC + ci) * 3 + kh) * 3 + kw]);
}

// x NCHW f32 -> xt NHWC bf16. Block = (b,h).
__global__ __launch_bounds__(256) void to_nhwc(const float* __restrict__ x,
                                               unsigned short* __restrict__ xt) {
  __shared__ unsigned short l[64 * 162];
  int bh = blockIdx.x; int b = bh / NH, h = bh % NH;
  for (int i = threadIdx.x; i < 64 * NW; i += 256) {
    int ci = i / NW, w = i % NW;
    l[ci * 162 + w] = f2bf(x[(((size_t)b * NC + ci) * NH + h) * NW + w]);
  }
  __syncthreads();
  unsigned short* o = xt + ((size_t)b * NH + h) * NW * NC;
  for (int i = threadIdx.x; i < NW * 8; i += 256) {
    int w = i >> 3, s = i & 7;
    u16x8 v;
#pragma unroll
    for (int j = 0; j < 8; ++j) v[j] = l[(s * 8 + j) * 162 + w];
    *(u16x8*)&o[w * 64 + s * 8] = v;
  }
}

// ---------------------------------------------------------------------------
// Sliding-row implicit-GEMM conv3x3 (SAME) via MFMA 16x16x32 bf16.
// Block = (b, 10-h strip, 80-w half). 256 thr = 4 waves; wave = ct (16 co).
// Ring: 4 row slots [82 wc][64 ci] bf16, XOR-swizzled (granule ^= wc&7).
// Weights in registers (18 frags/wave). 1 ds_read_b128 : 1 MFMA.
// ---------------------------------------------------------------------------
template<bool FINAL>
__global__ __launch_bounds__(256, 2) void conv3x3_mfma2(
    const unsigned short* __restrict__ in_nhwc, const unsigned short* __restrict__ apk,
    const float* __restrict__ gg, const float* __restrict__ bbeta,
    const float* __restrict__ mmean, const float* __restrict__ vvar,
    void* __restrict__ outv, const float* __restrict__ scores,
    const float* __restrict__ xres)
{
  __shared__ unsigned short ring[4 * 82 * 64];   // 41,984 B
  __shared__ unsigned short epi[80 * 72];        // 11,520 B

  const int t = threadIdx.x, lane = t & 63, wave = t >> 6;
  const int q = lane >> 4, col = lane & 15;

  int g = blockIdx.x;                    // 512 = 8 * 64, bijective XCD swizzle
  int sw = (g & 7) * 64 + (g >> 3);
  const int b = sw >> 5, strip = (sw >> 1) & 15, wh = sw & 1;
  const int h0 = strip * 10, w0 = wh * 80;

  // per-thread BN/score params (co = wave*16 + q*4 + reg)
  float scR[4], shR[4], scoR[4];
#pragma unroll
  for (int r = 0; r < 4; ++r) {
    int co = wave * 16 + q * 4 + r;
    float s = gg[co] * rsqrtf(vvar[co] + 1e-5f);
    scR[r] = s; shR[r] = bbeta[co] - mmean[co] * s;
    scoR[r] = FINAL ? scores[b * NC + co] : 0.f;
  }

  // weights -> registers, once
  bf16x8 wf[18];
#pragma unroll
  for (int ks = 0; ks < 18; ++ks)
    wf[ks] = *(const bf16x8*)&apk[((size_t)(wave * 18 + ks) * 64 + lane) * 8];

  const unsigned short* inb = in_nhwc + (size_t)b * NH * NW * 64;

#define STG_LOAD(K, SV, SA, ACT)                                              \
  { int c = wave + 4 * K;                                                     \
    if (c < 11) {                                                             \
      int s8 = lane & 7; int wl; bool lact = true;                            \
      if (c < 10) wl = c * 8 + (lane >> 3);                                   \
      else { wl = (lane & 8) ? 80 : -1; lact = lane < 16; }                   \
      int wcc = wl + 1, wsrc = w0 + wl;                                       \
      SA = slot + wcc * 64 + ((s8 ^ (wcc & 7)) << 3);                         \
      ACT = lact;                                                             \
      bool ok = rowok && lact && (unsigned)wsrc < (unsigned)NW;               \
      if (ok) SV = *(const u16x8*)&inb[((size_t)rowc * NW + wsrc) * 64 + s8 * 8]; \
    } else ACT = false; }
#define STG_WRITE(K, SV, SA, ACT)                                             \
  { int c = wave + 4 * K; if (c < 11 && ACT) *(u16x8*)&ring[SA] = SV; }

  // prologue: rows h0-1 .. h0+1
  for (int rr = 0; rr < 3; ++rr) {
    int row = h0 - 1 + rr;
    bool rowok = row >= 0;              // row <= 159 always here
    int rowc = row < 0 ? 0 : row;
    int slot = (row & 3) * 5248;
    u16x8 v0 = {}, v1 = {}, v2 = {}; int a0 = 0, a1 = 0, a2 = 0;
    bool c0 = false, c1 = false, c2 = false;
    STG_LOAD(0, v0, a0, c0) STG_LOAD(1, v1, a1, c1) STG_LOAD(2, v2, a2, c2)
    STG_WRITE(0, v0, a0, c0) STG_WRITE(1, v1, a1, c1) STG_WRITE(2, v2, a2, c2)
  }
  __syncthreads();

  for (int h = h0; h < h0 + 10; ++h) {
    // phase 1: issue loads for row h+2 (T14 async-stage)
    int row = h + 2;
    bool rowok = row <= NH - 1;
    int rowc = row > NH - 1 ? NH - 1 : row;
    int slot = (row & 3) * 5248;
    u16x8 v0 = {}, v1 = {}, v2 = {}; int a0 = 0, a1 = 0, a2 = 0;
    bool c0 = false, c1 = false, c2 = false;
    STG_LOAD(0, v0, a0, c0) STG_LOAD(1, v1, a1, c1) STG_LOAD(2, v2, a2, c2)

    // phase 2: compute (ring rows h-1..h+1)
    int rbs[3] = { ((h - 1) & 3) * 5248, (h & 3) * 5248, ((h + 1) & 3) * 5248 };
    f32x4 acc[5];
#pragma unroll
    for (int wt = 0; wt < 5; ++wt) acc[wt] = (f32x4){0.f, 0.f, 0.f, 0.f};
#pragma unroll
    for (int kh = 0; kh < 3; ++kh) {
#pragma unroll
      for (int kw = 0; kw < 3; ++kw) {
#pragma unroll
        for (int cih = 0; cih < 2; ++cih) {
          const int ks = (kh * 3 + kw) * 2 + cih;
          int wcb = col + kw;
          int ea = rbs[kh] + wcb * 64 + (((cih << 2) + q) ^ (wcb & 7)) * 8;
          const bf16x8* bp = (const bf16x8*)&ring[ea];
#pragma unroll
          for (int wt = 0; wt < 5; ++wt)
            acc[wt] = __builtin_amdgcn_mfma_f32_16x16x32_bf16(wf[ks], bp[wt * 128], acc[wt], 0, 0, 0);
        }
      }
    }

    // phase 3: complete staging (vmcnt waited here, hidden under compute)
    STG_WRITE(0, v0, a0, c0) STG_WRITE(1, v1, a1, c1) STG_WRITE(2, v2, a2, c2)

    if constexpr (!FINAL) {
      // epilogue: silu(bn1(acc)) -> epi LDS transpose -> y NHWC
#pragma unroll
      for (int wt = 0; wt < 5; ++wt) {
        u16x4 ev;
#pragma unroll
        for (int r = 0; r < 4; ++r) {
          float z = scR[r] * acc[wt][r] + shR[r];
          ev[r] = f2bf(z / (1.f + __expf(-z)));
        }
        *(u16x4*)&epi[(wt * 16 + col) * 72 + wave * 16 + q * 4] = ev;
      }
      __syncthreads();
      unsigned short* yo = (unsigned short*)outv + ((size_t)b * NH + h) * NW * 64 + (size_t)w0 * 64;
      for (int i = t; i < 640; i += 256) {
        int w = i >> 3, s = i & 7;
        *(u16x8*)&yo[w * 64 + s * 8] = *(const u16x8*)&epi[w * 72 + s * 8];
      }
      __syncthreads();
    } else {
      // final: out = x + relu(bn2(score*conv + y)); y read from ring (row h)
      float* outp = (float*)outv;
      int rb1 = (h & 3) * 5248;
#pragma unroll
      for (int wt = 0; wt < 5; ++wt) {
        int wcc = wt * 16 + col + 1;
        int gr = (wave * 2 + (q >> 1)) ^ (wcc & 7);
        u16x4 yv = *(const u16x4*)&ring[rb1 + wcc * 64 + gr * 8 + (q & 1) * 4];
#pragma unroll
        for (int r = 0; r < 4; ++r) {
          int co = wave * 16 + q * 4 + r;
          float rv = scoR[r] * acc[wt][r] + bf2f(yv[r]);
          float rb_ = scR[r] * rv + shR[r];
          rb_ = fmaxf(rb_, 0.f);
          size_t oi = (((size_t)b * NC + co) * NH + h) * NW + w0 + wt * 16 + col;
          outp[oi] = xres[oi] + rb_;
        }
      }
      __syncthreads();
    }
  }
#undef STG_LOAD
#undef STG_WRITE
}

// ycol[b][w][c] = sum_h y_nhwc[b][h][w][c]
__global__ void colsum_kernel(const unsigned short* __restrict__ y, float* __restrict__ ycol) {
  int id = blockIdx.x * 256 + threadIdx.x;
  if (id >= NB * NW * NC) return;
  int c = id & 63, bw = id >> 6;
  int w = bw % NW, b = bw / NW;
  float s = 0.f;
  for (int h = 0; h < NH; ++h)
    s += bf2f(y[(((size_t)b * NH + h) * NW + w) * 64 + c]);
  ycol[id] = s;
}

// wks[o] = sum_j wk[j][o]
__global__ void wksum_kernel(const float* __restrict__ wk, float* __restrict__ wks) {
  int o = blockIdx.x * 256 + threadIdx.x;
  if (o >= 576) return;
  float s = 0.f;
  for (int j = 0; j < NC; ++j) s += wk[(size_t)j * 576 + o];
  wks[o] = s;
}

__global__ __launch_bounds__(256, 1) void scores_kernel(
    const unsigned short* __restrict__ y, const float* __restrict__ ycol,
    const float* __restrict__ wks, const float* __restrict__ wq,
    float* __restrict__ scores)
{
  __shared__ float Z[NC * 3 * 162];
  __shared__ float ks[NW];
  __shared__ float U[576];
  const int b = blockIdx.x, t = threadIdx.x;

  for (int idx = t; idx < NC * 3 * 162; idx += 256) {
    int lw = idx % 162;
    int kh = (idx / 162) % 3;
    int i  = idx / (162 * 3);
    int w = lw - 1;
    float val = 0.f;
    if ((unsigned)w < (unsigned)NW) {
      val = ycol[((size_t)b * NW + w) * 64 + i];
      if (kh == 0) val -= bf2f(y[(((size_t)b * NH + (NH - 1)) * NW + w) * 64 + i]);
      if (kh == 2) val -= bf2f(y[(((size_t)b * NH) * NW + w) * 64 + i]);
    }
    Z[idx] = val;
  }
  __syncthreads();

  if (t < NW) {
    float s = 0.f;
    for (int ik = 0; ik < NC * 3; ++ik) {
      const float* zr = &Z[ik * 162 + t];
      const float* wp = &wks[ik * 3];
      s += wp[0] * zr[0] + wp[1] * zr[1] + wp[2] * zr[2];
    }
    ks[t] = s;
  }
  __syncthreads();

  for (int o = t; o < 576; o += 256) {
    int kw = o % 3; int ik = o / 3;
    const float* zr = &Z[ik * 162 + kw];
    float s = 0.f;
    for (int w = 0; w < NW; ++w) s += zr[w] * ks[w];
    U[o] = s;
  }
  __syncthreads();

  if (t < NC) {
    const float* wp = wq + (size_t)t * 576;
    float s = 0.f;
    for (int o = 0; o < 576; ++o) s += wp[o] * U[o];
    const float scale = 1.0f / (sqrtf((float)NW) * (float)NH * (float)NH);
    float f = s * scale;
    float mx = f;
#pragma unroll
    for (int off = 32; off; off >>= 1) mx = fmaxf(mx, __shfl_xor(mx, off));
    float e = __expf(f - mx);
    float sm = e;
#pragma unroll
    for (int off = 32; off; off >>= 1) sm += __shfl_xor(sm, off);
    scores[b * NC + t] = e / sm;
  }
}

extern "C" void kernel_launch(void* const* d_in, const int* in_sizes, int n_in,
                              void* d_out, int out_size, void* d_ws, size_t ws_size,
                              hipStream_t stream) {
  const float* x  = (const float*)d_in[0];
  const float* w1 = (const float*)d_in[1];
  const float* g1 = (const float*)d_in[2];
  const float* b1 = (const float*)d_in[3];
  const float* m1 = (const float*)d_in[4];
  const float* v1 = (const float*)d_in[5];
  const float* wq = (const float*)d_in[6];
  const float* wk = (const float*)d_in[7];
  const float* wv = (const float*)d_in[8];
  const float* g2 = (const float*)d_in[9];
  const float* b2 = (const float*)d_in[10];
  const float* m2 = (const float*)d_in[11];
  const float* v2 = (const float*)d_in[12];
  float* out = (float*)d_out;

  // ws: apk1 | apk2 | ycol | wks | scr | xt(NHWC bf16) | y(NHWC bf16)  ~106 MB
  unsigned short* apk1 = (unsigned short*)d_ws;
  unsigned short* apk2 = apk1 + 36864;
  float* ycol = (float*)(apk2 + 36864);
  float* wks  = ycol + NB * NW * NC;
  float* scr  = wks + 576;
  unsigned short* xt = (unsigned short*)(scr + 1024);
  unsigned short* y  = xt + (size_t)NB * NH * NW * 64;

  pack_w_kernel<<<dim3(144), 256, 0, stream>>>(w1, apk1);
  pack_w_kernel<<<dim3(144), 256, 0, stream>>>(wv, apk2);
  to_nhwc<<<dim3(NB * NH), 256, 0, stream>>>(x, xt);

  conv3x3_mfma2<false><<<dim3(512), 256, 0, stream>>>(
      xt, apk1, g1, b1, m1, v1, (void*)y, nullptr, nullptr);

  colsum_kernel<<<dim3((NB * NW * NC + 255) / 256), 256, 0, stream>>>(y, ycol);
  wksum_kernel<<<dim3(3), 256, 0, stream>>>(wk, wks);
  scores_kernel<<<dim3(NB), 256, 0, stream>>>(y, ycol, wks, wq, scr);

  conv3x3_mfma2<true><<<dim3(512), 256, 0, stream>>>(
      y, apk2, g2, b2, m2, v2, (void*)out, scr, x);
}